// Round 14
// baseline (84.678 us; speedup 1.0000x reference)
//
#include <hip/hip_runtime.h>

#define EPS 1e-7f
#define NCH 29
#define SPB 256          // samples per block: 64 lanes x 4 packed (q = 0..3)
#define ROWA 17          // padded float4 stride per sample in chunk staging buffer

// MLP sizes: 7 -> 5 -> 4 -> 4 -> 3, per-channel weights.
// W0: [c][7][5]  b0: [c][5]
// W1: [c][5][4]  b1: [c][4]
// W2: [c][4][4]  b2: [c][4]
// W3: [c][4][3]  b3: [c][3]

typedef float f32x4 __attribute__((ext_vector_type(4)));

__device__ __forceinline__ f32x4 splat4(float v) { f32x4 r; r.x = v; r.y = v; r.z = v; r.w = v; return r; }
__device__ __forceinline__ f32x4 fma4(f32x4 a, f32x4 b, f32x4 c) {
    return __builtin_elementwise_fma(a, b, c);
}
__device__ __forceinline__ f32x4 max4(f32x4 a, f32x4 b) {
    return __builtin_elementwise_max(a, b);
}
__device__ __forceinline__ f32x4 expc4(f32x4 a) {
    f32x4 r; r.x = __expf(a.x); r.y = __expf(a.y); r.z = __expf(a.z); r.w = __expf(a.w); return r;
}
__device__ __forceinline__ f32x4 rcp4(f32x4 a) {
    f32x4 r;
    r.x = __builtin_amdgcn_rcpf(a.x); r.y = __builtin_amdgcn_rcpf(a.y);
    r.z = __builtin_amdgcn_rcpf(a.z); r.w = __builtin_amdgcn_rcpf(a.w);
    return r;
}

// Barrier ordering LDS traffic only (lgkmcnt), NOT global stores (vmcnt):
// chunk-k stores stay in flight underneath chunk-(k+1) compute.
__device__ __forceinline__ void barrier_lds_only() {
    asm volatile("s_waitcnt lgkmcnt(0)\n\ts_barrier" ::: "memory");
}

// Quad-packed MLP: ONE weight stream (wave-uniform SGPRs) feeds FOUR samples
// (2x v_pk_fma_f32 per weight). Per-sample s_load/wait cost is half of the
// f32x2 version -- the amortization lever this round isolates.
__device__ __forceinline__ void mlp7q(const f32x4 x[7],
    const float* __restrict__ W0, const float* __restrict__ b0,
    const float* __restrict__ W1, const float* __restrict__ b1,
    const float* __restrict__ W2, const float* __restrict__ b2,
    const float* __restrict__ W3, const float* __restrict__ b3,
    f32x4 e[3])
{
    const f32x4 zero = splat4(0.0f);
    f32x4 h0[5];
#pragma unroll
    for (int h = 0; h < 5; ++h) {
        f32x4 a = splat4(b0[h]);
#pragma unroll
        for (int f = 0; f < 7; ++f) a = fma4(x[f], splat4(W0[f * 5 + h]), a);
        h0[h] = max4(a, zero);
    }
    f32x4 h1[4];
#pragma unroll
    for (int k = 0; k < 4; ++k) {
        f32x4 a = splat4(b1[k]);
#pragma unroll
        for (int h = 0; h < 5; ++h) a = fma4(h0[h], splat4(W1[h * 4 + k]), a);
        h1[k] = max4(a, zero);
    }
    f32x4 h2[4];
#pragma unroll
    for (int k = 0; k < 4; ++k) {
        f32x4 a = splat4(b2[k]);
#pragma unroll
        for (int h = 0; h < 4; ++h) a = fma4(h1[h], splat4(W2[h * 4 + k]), a);
        h2[k] = max4(a, zero);
    }
    f32x4 l[3];
#pragma unroll
    for (int k = 0; k < 3; ++k) {
        f32x4 a = splat4(b3[k]);
#pragma unroll
        for (int h = 0; h < 4; ++h) a = fma4(h2[h], splat4(W3[h * 3 + k]), a);
        l[k] = a;
    }
    f32x4 m = max4(l[0], max4(l[1], l[2]));
    f32x4 e0 = expc4(l[0] - m);
    f32x4 e1 = expc4(l[1] - m);
    f32x4 e2 = expc4(l[2] - m);
    f32x4 rs = rcp4(e0 + e1 + e2);
    e[0] = e0 * rs; e[1] = e1 * rs; e[2] = e2 * rs;
}

// VGPR cap 128 (4 waves/EU); 2 blocks/CU (LDS 69.6KB and VGPR both allow 2).
__global__ __launch_bounds__(512, 4) void lps_kernel(
    const float* __restrict__ tau, const float* __restrict__ mu, const float* __restrict__ mu_bar,
    const float* __restrict__ lw, const float* __restrict__ h2o, const float* __restrict__ o3,
    const float* __restrict__ co2, const float* __restrict__ uu, const float* __restrict__ n2o,
    const float* __restrict__ ch4,
    const float* __restrict__ Wd0, const float* __restrict__ bd0,
    const float* __restrict__ Wf0, const float* __restrict__ bf0,
    const float* __restrict__ Wd1, const float* __restrict__ bd1,
    const float* __restrict__ Wf1, const float* __restrict__ bf1,
    const float* __restrict__ Wd2, const float* __restrict__ bd2,
    const float* __restrict__ Wf2, const float* __restrict__ bf2,
    const float* __restrict__ Wd3, const float* __restrict__ bd3,
    const float* __restrict__ Wf3, const float* __restrict__ bf3,
    float* __restrict__ out, int N)
{
    __shared__ __align__(16) float4 obuf[SPB * ROWA];   // 69632 B

    const int tid  = threadIdx.x;
    const int lane = tid & 63;
    const int wid  = __builtin_amdgcn_readfirstlane(tid >> 6);   // 0..7

    const long long base = (long long)blockIdx.x * SPB;
    int iq[4];
#pragma unroll
    for (int q = 0; q < 4; ++q) {
        const long long s = base + lane + 64 * q;
        iq[q] = (s < N) ? (int)s : (N - 1);
    }

    f32x4 mu4, mub4;
    mu4.x  = mu[iq[0]];      mu4.y  = mu[iq[1]];      mu4.z  = mu[iq[2]];      mu4.w  = mu[iq[3]];
    mub4.x = mu_bar[iq[0]];  mub4.y = mu_bar[iq[1]];  mub4.z = mu_bar[iq[2]];  mub4.w = mu_bar[iq[3]];
    const f32x4 rmu4  = rcp4(mu4 + splat4(EPS));
    const f32x4 rmub4 = rcp4(mub4 + splat4(EPS));

    f32x4 cons4[7];
#pragma unroll
    for (int q = 0; q < 4; ++q) {
        cons4[0][q] = lw[iq[q]];
        cons4[1][q] = h2o[iq[q]];
        cons4[2][q] = o3[iq[q]];
        cons4[3][q] = co2[iq[q]];
        cons4[4][q] = uu[iq[q]];
        cons4[5][q] = n2o[iq[q]];
        cons4[6][q] = ch4[iq[q]];
    }

    int nsamp = N - (int)base;
    if (nsamp > SPB) nsamp = SPB;
    float4* out4 = (float4*)out;

    // 4 chunk-phases: compute 8 channels (x4 samples) -> lgkm barrier ->
    // issue stores (fire-and-forget, no vmcnt drain) -> lgkm barrier.
#pragma unroll
    for (int k = 0; k < 4; ++k) {
        const int c = k * 8 + wid;            // wave-uniform channel
        if (c < NCH) {
            f32x4 tau4;
            tau4.x = tau[(size_t)iq[0] * NCH + c];
            tau4.y = tau[(size_t)iq[1] * NCH + c];
            tau4.z = tau[(size_t)iq[2] * NCH + c];
            tau4.w = tau[(size_t)iq[3] * NCH + c];
            const f32x4 td4 = expc4(-(tau4 * rmu4));
            const f32x4 tf4 = expc4(-(tau4 * rmub4));

            f32x4 x4[7];
            f32x4 ed[3], ef[3];
#pragma unroll
            for (int f = 0; f < 7; ++f) x4[f] = cons4[f] * rmu4;
            mlp7q(x4, Wd0 + c * 35, bd0 + c * 5, Wd1 + c * 20, bd1 + c * 4,
                      Wd2 + c * 16, bd2 + c * 4, Wd3 + c * 12, bd3 + c * 3, ed);
#pragma unroll
            for (int f = 0; f < 7; ++f) x4[f] = cons4[f] * rmub4;
            mlp7q(x4, Wf0 + c * 35, bf0 + c * 5, Wf1 + c * 20, bf1 + c * 4,
                      Wf2 + c * 16, bf2 + c * 4, Wf3 + c * 12, bf3 + c * 3, ef);

            const int r = (c - k * 8) * 2;    // local slot 0..15
#pragma unroll
            for (int q = 0; q < 4; ++q) {
                const int row = lane + 64 * q;
                obuf[row * ROWA + r]     = make_float4(td4[q], tf4[q], ed[0][q], ed[1][q]);
                obuf[row * ROWA + r + 1] = make_float4(ed[2][q], ef[0][q], ef[1][q], ef[2][q]);
            }
        }

        barrier_lds_only();

        // issue chunk-k stores (fire-and-forget)
        if (nsamp > 0) {
            if (k < 3) {
                const int tot = nsamp * 16;
                for (int i = tid; i < tot; i += 512) {
                    const int s = i >> 4, rr = i & 15;
                    out4[(base + s) * 58 + k * 16 + rr] = obuf[s * ROWA + rr];
                }
            } else {
                const int tot = nsamp * 10;   // 5 channels -> 10 f4 per sample
                for (int i = tid; i < tot; i += 512) {
                    const int s = i / 10, rr = i - s * 10;
                    out4[(base + s) * 58 + 48 + rr] = obuf[s * ROWA + rr];
                }
            }
        }

        barrier_lds_only();   // flush reads done -> obuf reusable
    }
}

extern "C" void kernel_launch(void* const* d_in, const int* in_sizes, int n_in,
                              void* d_out, int out_size, void* d_ws, size_t ws_size,
                              hipStream_t stream) {
    const float* tau    = (const float*)d_in[0];
    const float* mu     = (const float*)d_in[1];
    const float* mu_bar = (const float*)d_in[2];
    const float* lw     = (const float*)d_in[3];
    const float* h2o    = (const float*)d_in[4];
    const float* o3     = (const float*)d_in[5];
    const float* co2    = (const float*)d_in[6];
    const float* uu     = (const float*)d_in[7];
    const float* n2o    = (const float*)d_in[8];
    const float* ch4    = (const float*)d_in[9];

    const float* Wd0 = (const float*)d_in[10];
    const float* bd0 = (const float*)d_in[11];
    const float* Wf0 = (const float*)d_in[12];
    const float* bf0 = (const float*)d_in[13];
    const float* Wd1 = (const float*)d_in[14];
    const float* bd1 = (const float*)d_in[15];
    const float* Wf1 = (const float*)d_in[16];
    const float* bf1 = (const float*)d_in[17];
    const float* Wd2 = (const float*)d_in[18];
    const float* bd2 = (const float*)d_in[19];
    const float* Wf2 = (const float*)d_in[20];
    const float* bf2 = (const float*)d_in[21];
    const float* Wd3 = (const float*)d_in[22];
    const float* bd3 = (const float*)d_in[23];
    const float* Wf3 = (const float*)d_in[24];
    const float* bf3 = (const float*)d_in[25];

    float* out = (float*)d_out;
    int N = in_sizes[1];  // mu has N elements

    int blocks = (N + SPB - 1) / SPB;
    lps_kernel<<<blocks, 512, 0, stream>>>(
        tau, mu, mu_bar, lw, h2o, o3, co2, uu, n2o, ch4,
        Wd0, bd0, Wf0, bf0, Wd1, bd1, Wf1, bf1,
        Wd2, bd2, Wf2, bf2, Wd3, bd3, Wf3, bf3,
        out, N);
}

// Round 15
// 82.740 us; speedup vs baseline: 1.0234x; 1.0234x over previous
//
#include <hip/hip_runtime.h>

#define EPS 1e-7f
#define NCH 29
#define SPB 128          // samples per block: 64 lanes x 2 packed (group0, group1)
#define ROWA 17          // padded float4 stride per sample in chunk staging buffer

// MLP sizes: 7 -> 5 -> 4 -> 4 -> 3, per-channel weights.
// Prologue kernel converts all weights to duplicated f16 pairs (w,w) packed in
// one dword each, laid out per (set, channel) as 99 consecutive dwords:
//   W0[7][5]@0  b0@35  W1[5][4]@40  b1@60  W2[4][4]@64  b2@80  W3[4][3]@84  b3@96
// Main kernel s_loads these dwords (wave-uniform) and feeds v_pk_fma_f16:
// 2 f16 FMAs/lane/cycle = 2x the f32 pipe -> halves MLP exec time.

typedef float    f32x2 __attribute__((ext_vector_type(2)));
typedef _Float16 f16;
typedef f16      f16x2 __attribute__((ext_vector_type(2)));

__device__ __forceinline__ f32x2 splat2(float v) { f32x2 r; r.x = v; r.y = v; return r; }
__device__ __forceinline__ f32x2 expc2(f32x2 a) {
    f32x2 r; r.x = __expf(a.x); r.y = __expf(a.y); return r;
}
__device__ __forceinline__ f32x2 rcp2(f32x2 a) {
    f32x2 r; r.x = __builtin_amdgcn_rcpf(a.x); r.y = __builtin_amdgcn_rcpf(a.y); return r;
}
__device__ __forceinline__ f16x2 hbc(unsigned w) { return __builtin_bit_cast(f16x2, w); }
__device__ __forceinline__ f16x2 hfma(f16x2 a, f16x2 b, f16x2 c) {
    return __builtin_elementwise_fma(a, b, c);   // v_pk_fma_f16
}
__device__ __forceinline__ f16x2 hmax(f16x2 a, f16x2 b) {
    return __builtin_elementwise_max(a, b);      // v_pk_max_f16
}

// Barrier ordering LDS traffic only (lgkmcnt), NOT global stores (vmcnt).
__device__ __forceinline__ void barrier_lds_only() {
    asm volatile("s_waitcnt lgkmcnt(0)\n\ts_barrier" ::: "memory");
}

// ---- prologue: f32 weights -> duplicated f16-pair dwords in d_ws ----
__global__ void wprep_kernel(
    const float* __restrict__ Wd0, const float* __restrict__ bd0,
    const float* __restrict__ Wd1, const float* __restrict__ bd1,
    const float* __restrict__ Wd2, const float* __restrict__ bd2,
    const float* __restrict__ Wd3, const float* __restrict__ bd3,
    const float* __restrict__ Wf0, const float* __restrict__ bf0,
    const float* __restrict__ Wf1, const float* __restrict__ bf1,
    const float* __restrict__ Wf2, const float* __restrict__ bf2,
    const float* __restrict__ Wf3, const float* __restrict__ bf3,
    unsigned* __restrict__ ws)
{
    const int i = blockIdx.x * blockDim.x + threadIdx.x;
    const int TOT = 2 * NCH * 99;
    if (i >= TOT) return;
    const int set = i / (NCH * 99);
    const int r   = i - set * (NCH * 99);
    const int c   = r / 99;
    const int o   = r - c * 99;

    const float* W0 = set ? Wf0 : Wd0; const float* B0 = set ? bf0 : bd0;
    const float* W1 = set ? Wf1 : Wd1; const float* B1 = set ? bf1 : bd1;
    const float* W2 = set ? Wf2 : Wd2; const float* B2 = set ? bf2 : bd2;
    const float* W3 = set ? Wf3 : Wd3; const float* B3 = set ? bf3 : bd3;

    float v;
    if      (o < 35) v = W0[c * 35 + o];
    else if (o < 40) v = B0[c * 5  + (o - 35)];
    else if (o < 60) v = W1[c * 20 + (o - 40)];
    else if (o < 64) v = B1[c * 4  + (o - 60)];
    else if (o < 80) v = W2[c * 16 + (o - 64)];
    else if (o < 84) v = B2[c * 4  + (o - 80)];
    else if (o < 96) v = W3[c * 12 + (o - 84)];
    else             v = B3[c * 3  + (o - 96)];

    const unsigned short h = __builtin_bit_cast(unsigned short, (f16)v);
    ws[i] = (unsigned)h | ((unsigned)h << 16);
}

// f16-packed 2-sample MLP. Weights: 99 wave-uniform dwords (s_load/SGPR).
// Softmax finish in f32 for accuracy.
__device__ __forceinline__ void mlp7h(const f16x2 x[7],
    const unsigned* __restrict__ wb, f32x2 e[3])
{
    f16x2 zero; zero.x = (f16)0; zero.y = (f16)0;
    f16x2 h0[5];
#pragma unroll
    for (int h = 0; h < 5; ++h) {
        f16x2 a = hbc(wb[35 + h]);
#pragma unroll
        for (int f = 0; f < 7; ++f) a = hfma(x[f], hbc(wb[f * 5 + h]), a);
        h0[h] = hmax(a, zero);
    }
    f16x2 h1[4];
#pragma unroll
    for (int k = 0; k < 4; ++k) {
        f16x2 a = hbc(wb[60 + k]);
#pragma unroll
        for (int f = 0; f < 5; ++f) a = hfma(h0[f], hbc(wb[40 + f * 4 + k]), a);
        h1[k] = hmax(a, zero);
    }
    f16x2 h2[4];
#pragma unroll
    for (int k = 0; k < 4; ++k) {
        f16x2 a = hbc(wb[80 + k]);
#pragma unroll
        for (int f = 0; f < 4; ++f) a = hfma(h1[f], hbc(wb[64 + f * 4 + k]), a);
        h2[k] = hmax(a, zero);
    }
    f16x2 l[3];
#pragma unroll
    for (int k = 0; k < 3; ++k) {
        f16x2 a = hbc(wb[96 + k]);
#pragma unroll
        for (int f = 0; f < 4; ++f) a = hfma(h2[f], hbc(wb[84 + f * 3 + k]), a);
        l[k] = a;
    }
    // f32 softmax per packed half
    const float l0x = (float)l[0].x, l1x = (float)l[1].x, l2x = (float)l[2].x;
    const float l0y = (float)l[0].y, l1y = (float)l[1].y, l2y = (float)l[2].y;
    const float mx = fmaxf(l0x, fmaxf(l1x, l2x));
    const float my = fmaxf(l0y, fmaxf(l1y, l2y));
    const float e0x = __expf(l0x - mx), e1x = __expf(l1x - mx), e2x = __expf(l2x - mx);
    const float e0y = __expf(l0y - my), e1y = __expf(l1y - my), e2y = __expf(l2y - my);
    const float rsx = __builtin_amdgcn_rcpf(e0x + e1x + e2x);
    const float rsy = __builtin_amdgcn_rcpf(e0y + e1y + e2y);
    e[0].x = e0x * rsx; e[0].y = e0y * rsy;
    e[1].x = e1x * rsx; e[1].y = e1y * rsy;
    e[2].x = e2x * rsx; e[2].y = e2y * rsy;
}

// min 6 waves/EU -> VGPR cap 85 -> 24 waves/CU (3 blocks x 8 waves)
__global__ __launch_bounds__(512, 6) void lps_kernel(
    const float* __restrict__ tau, const float* __restrict__ mu, const float* __restrict__ mu_bar,
    const float* __restrict__ lw, const float* __restrict__ h2o, const float* __restrict__ o3,
    const float* __restrict__ co2, const float* __restrict__ uu, const float* __restrict__ n2o,
    const float* __restrict__ ch4,
    const unsigned* __restrict__ wh,   // f16-pair weights: [set][ch][99]
    float* __restrict__ out, int N)
{
    __shared__ __align__(16) float4 obuf[SPB * ROWA];   // 34816 B

    const int tid  = threadIdx.x;
    const int lane = tid & 63;
    const int wid  = __builtin_amdgcn_readfirstlane(tid >> 6);   // 0..7

    const long long base = (long long)blockIdx.x * SPB;
    const int s0 = (int)base + lane;
    const int s1 = s0 + 64;
    const int i0 = (s0 < N) ? s0 : (N - 1);
    const int i1 = (s1 < N) ? s1 : (N - 1);

    f32x2 mu2, mub2;
    mu2.x  = mu[i0];      mu2.y  = mu[i1];
    mub2.x = mu_bar[i0];  mub2.y = mu_bar[i1];
    const f32x2 rmu2  = rcp2(mu2 + splat2(EPS));
    const f32x2 rmub2 = rcp2(mub2 + splat2(EPS));

    // Build packed-f16 MLP inputs once (both halves of the pair = 2 samples).
    f16x2 xdh[7], xfh[7];
    {
        float c0, c1;
#define MKX(idx, arr) \
        c0 = arr[i0]; c1 = arr[i1]; \
        xdh[idx].x = (f16)(c0 * rmu2.x);  xdh[idx].y = (f16)(c1 * rmu2.y); \
        xfh[idx].x = (f16)(c0 * rmub2.x); xfh[idx].y = (f16)(c1 * rmub2.y);
        MKX(0, lw) MKX(1, h2o) MKX(2, o3) MKX(3, co2) MKX(4, uu) MKX(5, n2o) MKX(6, ch4)
#undef MKX
    }

    int nsamp = N - (int)base;
    if (nsamp > SPB) nsamp = SPB;
    float4* out4 = (float4*)out;

    // 4 chunk-phases: compute 8 channels -> lgkm barrier -> issue stores
    // (fire-and-forget) -> lgkm barrier. No vmcnt drain anywhere.
#pragma unroll
    for (int k = 0; k < 4; ++k) {
        const int c = k * 8 + wid;            // wave-uniform channel
        if (c < NCH) {
            f32x2 tau2;
            tau2.x = tau[(size_t)i0 * NCH + c];
            tau2.y = tau[(size_t)i1 * NCH + c];
            const f32x2 td2 = expc2(-(tau2 * rmu2));
            const f32x2 tf2 = expc2(-(tau2 * rmub2));

            f32x2 ed[3], ef[3];
            mlp7h(xdh, wh + c * 99, ed);
            mlp7h(xfh, wh + (NCH + c) * 99, ef);

            const int r = (c - k * 8) * 2;    // local slot 0..15
            obuf[lane * ROWA + r]            = make_float4(td2.x, tf2.x, ed[0].x, ed[1].x);
            obuf[lane * ROWA + r + 1]        = make_float4(ed[2].x, ef[0].x, ef[1].x, ef[2].x);
            obuf[(lane + 64) * ROWA + r]     = make_float4(td2.y, tf2.y, ed[0].y, ed[1].y);
            obuf[(lane + 64) * ROWA + r + 1] = make_float4(ed[2].y, ef[0].y, ef[1].y, ef[2].y);
        }

        barrier_lds_only();

        if (nsamp > 0) {
            if (k < 3) {
                const int tot = nsamp * 16;
                for (int i = tid; i < tot; i += 512) {
                    const int s = i >> 4, rr = i & 15;
                    out4[(base + s) * 58 + k * 16 + rr] = obuf[s * ROWA + rr];
                }
            } else {
                const int tot = nsamp * 10;   // 5 channels -> 10 f4 per sample
                for (int i = tid; i < tot; i += 512) {
                    const int s = i / 10, rr = i - s * 10;
                    out4[(base + s) * 58 + 48 + rr] = obuf[s * ROWA + rr];
                }
            }
        }

        barrier_lds_only();
    }
}

extern "C" void kernel_launch(void* const* d_in, const int* in_sizes, int n_in,
                              void* d_out, int out_size, void* d_ws, size_t ws_size,
                              hipStream_t stream) {
    const float* tau    = (const float*)d_in[0];
    const float* mu     = (const float*)d_in[1];
    const float* mu_bar = (const float*)d_in[2];
    const float* lw     = (const float*)d_in[3];
    const float* h2o    = (const float*)d_in[4];
    const float* o3     = (const float*)d_in[5];
    const float* co2    = (const float*)d_in[6];
    const float* uu     = (const float*)d_in[7];
    const float* n2o    = (const float*)d_in[8];
    const float* ch4    = (const float*)d_in[9];

    const float* Wd0 = (const float*)d_in[10];
    const float* bd0 = (const float*)d_in[11];
    const float* Wf0 = (const float*)d_in[12];
    const float* bf0 = (const float*)d_in[13];
    const float* Wd1 = (const float*)d_in[14];
    const float* bd1 = (const float*)d_in[15];
    const float* Wf1 = (const float*)d_in[16];
    const float* bf1 = (const float*)d_in[17];
    const float* Wd2 = (const float*)d_in[18];
    const float* bd2 = (const float*)d_in[19];
    const float* Wf2 = (const float*)d_in[20];
    const float* bf2 = (const float*)d_in[21];
    const float* Wd3 = (const float*)d_in[22];
    const float* bd3 = (const float*)d_in[23];
    const float* Wf3 = (const float*)d_in[24];
    const float* bf3 = (const float*)d_in[25];

    float* out = (float*)d_out;
    unsigned* wh = (unsigned*)d_ws;       // needs 2*29*99*4 = 22968 B
    int N = in_sizes[1];  // mu has N elements

    // prologue: convert weights to duplicated f16 pairs (every call; deterministic)
    const int TOT = 2 * NCH * 99;
    wprep_kernel<<<(TOT + 255) / 256, 256, 0, stream>>>(
        Wd0, bd0, Wd1, bd1, Wd2, bd2, Wd3, bd3,
        Wf0, bf0, Wf1, bf1, Wf2, bf2, Wf3, bf3, wh);

    int blocks = (N + SPB - 1) / SPB;
    lps_kernel<<<blocks, 512, 0, stream>>>(
        tau, mu, mu_bar, lw, h2o, o3, co2, uu, n2o, ch4,
        wh, out, N);
}